// Round 4
// baseline (115.367 us; speedup 1.0000x reference)
//
#include <hip/hip_runtime.h>
#include <hip/hip_bf16.h>

// Sum each consecutive group of 4 rows of a (N, C) fp32 matrix -> (N/4, C),
// and gather pids[::4] (written as float: the harness reads d_out flat as f32).
//
// N = 65536, C = 2048. Pure streaming, no reuse -> non-temporal everything.
// One block per output row: 256 threads x 2 vec4 columns each (= 512 vec4 =
// 2048 floats). 8 NT loads issued back-to-back per thread for deep MLP;
// thread 0 fuses the pids gather (kills the second kernel launch).

typedef float f32x4 __attribute__((ext_vector_type(4)));

__global__ void __launch_bounds__(256)
feat_group4_sum_kernel(const f32x4* __restrict__ in,
                       f32x4* __restrict__ out_feat,
                       const int* __restrict__ pids,
                       float* __restrict__ out_pids,
                       int c4)  // C/4 vec4s per row
{
    const int g = blockIdx.x;            // output row (group)
    const int t = threadIdx.x;
    const int c0 = t;
    const int c1 = t + blockDim.x;

    const f32x4* __restrict__ base = in + (size_t)g * 4 * c4;
    f32x4* __restrict__ ob = out_feat + (size_t)g * c4;

    // Issue all 8 loads before any arithmetic -> 8 outstanding vmem ops.
    f32x4 a0 = __builtin_nontemporal_load(base + c0);
    f32x4 b0 = __builtin_nontemporal_load(base + c4 + c0);
    f32x4 d0 = __builtin_nontemporal_load(base + 2 * c4 + c0);
    f32x4 e0 = __builtin_nontemporal_load(base + 3 * c4 + c0);
    f32x4 a1 = __builtin_nontemporal_load(base + c1);
    f32x4 b1 = __builtin_nontemporal_load(base + c4 + c1);
    f32x4 d1 = __builtin_nontemporal_load(base + 2 * c4 + c1);
    f32x4 e1 = __builtin_nontemporal_load(base + 3 * c4 + c1);

    __builtin_nontemporal_store((a0 + b0) + (d0 + e0), ob + c0);
    __builtin_nontemporal_store((a1 + b1) + (d1 + e1), ob + c1);

    if (t == 0) {
        out_pids[g] = (float)pids[(size_t)g * 4];
    }
}

extern "C" void kernel_launch(void* const* d_in, const int* in_sizes, int n_in,
                              void* d_out, int out_size, void* d_ws, size_t ws_size,
                              hipStream_t stream) {
    const float* features = (const float*)d_in[0];
    const int*   pids     = (const int*)d_in[1];

    const int N = in_sizes[1];          // 65536 (pids has N elements)
    const int C = in_sizes[0] / N;      // 2048
    const int G = N / 4;                // 16384 output rows
    const int c4 = C / 4;               // 512 vec4s per row (2 per thread)

    float* out_feat_f = (float*)d_out;
    float* out_pids_f = out_feat_f + (size_t)G * C;

    feat_group4_sum_kernel<<<G, 256, 0, stream>>>(
        (const f32x4*)features, (f32x4*)out_feat_f, pids, out_pids_f, c4);
}